// Round 7
// baseline (408.644 us; speedup 1.0000x reference)
//
#include <hip/hip_runtime.h>
#include <hip/hip_bf16.h>
#include <math.h>

#define B_   16
#define N_   1024
#define H_   4
#define D240 240

typedef unsigned short ushort;
typedef __attribute__((ext_vector_type(8))) short bf16x8;
typedef __attribute__((ext_vector_type(8))) unsigned short u16x8;
typedef __attribute__((ext_vector_type(4))) float f32x4;

__device__ __forceinline__ ushort f2b(float v) {
  __hip_bfloat16 h = __float2bfloat16(v);
  return *reinterpret_cast<ushort*>(&h);
}

__device__ __forceinline__ bf16x8 cvt8b(float4 a, float4 b) {
  u16x8 w;
  w[0] = f2b(a.x); w[1] = f2b(a.y); w[2] = f2b(a.z); w[3] = f2b(a.w);
  w[4] = f2b(b.x); w[5] = f2b(b.y); w[6] = f2b(b.z); w[7] = f2b(b.w);
  return *reinterpret_cast<bf16x8*>(&w);
}

__device__ __forceinline__ void gload16(const void* g, void* s) {
  __builtin_amdgcn_global_load_lds((const __attribute__((address_space(1))) void*)g,
                                   (__attribute__((address_space(3))) void*)s, 16, 0, 0);
}

// ---------------------------------------------------------------------------
// conv_weights: Wk_b | Wv_b | Wq_bd (block-diag per head) | Wo_b (col-permuted)
// ---------------------------------------------------------------------------
__global__ __launch_bounds__(256) void conv_weights(
    const float* __restrict__ Wk, const float* __restrict__ Wv,
    const float* __restrict__ q1, const float* __restrict__ q2,
    const float* __restrict__ q3, const float* __restrict__ q4,
    const float* __restrict__ o1, const float* __restrict__ o2,
    const float* __restrict__ o3, const float* __restrict__ o4,
    ushort* __restrict__ wts) {
  long i = (long)blockIdx.x * 256 + threadIdx.x;
  if (i >= 716800) return;
  float v = 0.f;
  if (i < 122880) {
    const float* src = (i < 61440) ? Wk : Wv;
    long j = (i < 61440) ? i : i - 61440;
    int r = j / 256, k = j % 256;
    if (k < 240) v = src[(long)r * 240 + k];
  } else if (i < 368640) {
    long j = i - 122880;
    int h = j / 61440; int rem = j % 61440;
    int r = rem / 256, k = rem % 256;
    int s = r < 16 ? 0 : r < 48 ? 1 : r < 112 ? 2 : 3;
    const int dss[4] = {16, 32, 64, 128};
    const int qf[4]  = {0, 16, 48, 112};
    const float* qs[4] = {q1, q2, q3, q4};
    int d = dss[s], off = qf[s];
    if (k >= off && k < off + d)
      v = qs[s][((long)(h * d + (r - off))) * d + (k - off)];
  } else {
    long j = i - 368640;
    int s = j < 4096 ? 0 : j < 20480 ? 1 : j < 86016 ? 2 : 3;
    const long base[4] = {0, 4096, 20480, 86016};
    const int cs[4] = {64, 128, 256, 512};
    const float* os[4] = {o1, o2, o3, o4};
    long rem = j - base[s];
    int c = cs[s], d = c >> 2;
    int e = rem / c, kk = rem % c;
    v = os[s][(long)e * c + (kk % d) * 4 + kk / d];
  }
  wts[i] = f2b(v);
}

// ---------------------------------------------------------------------------
// proj_wg_direct: barrier-free, LDS-free projection core. A = weight bf16
// (direct bf16x8 fragment loads, L2-hot), B = fp32 gather (direct 2x float4
// + cvt, bit-identical to staged path). K=256 fully unrolled; no syncthreads,
// no vmcnt(0) drain -> wave-async streaming MFMA. gmode 0: heads(emb_all),
// gmode 1: emb(e1..e4).
// ---------------------------------------------------------------------------
__device__ __forceinline__ void proj_wg_direct(
    const ushort* __restrict__ Aw, int M,
    const float* __restrict__ emb_all,
    const float* __restrict__ e1, const float* __restrict__ e2,
    const float* __restrict__ e3, const float* __restrict__ e4,
    int gmode, int b, int h,
    ushort* __restrict__ C, long ldc, int m0, int n0)
{
  const int tid = threadIdx.x;
  const int l = tid & 63, w = tid >> 6;
  const int wy = w >> 1, wx = w & 1;
  const int kq = (l >> 4) * 8;     // k sub-offset within 32-wide step

  f32x4 acc[4][4];
  #pragma unroll
  for (int i = 0; i < 4; ++i)
    #pragma unroll
    for (int j = 0; j < 4; ++j) acc[i][j] = (f32x4)0.f;

  // A fragment row pointers (clamped rows; clamped output rows skipped later)
  const ushort* ap[4];
  #pragma unroll
  for (int i = 0; i < 4; ++i) {
    int r = m0 + wy * 64 + i * 16 + (l & 15);
    r = r < M ? r : M - 1;
    ap[i] = Aw + (long)r * 256 + kq;
  }
  // B gather row bases (full 0..1023 range, no clamp)
  long rbn[4];
  #pragma unroll
  for (int j = 0; j < 4; ++j) {
    int n = n0 + wx * 64 + j * 16 + (l & 15);
    rbn[j] = (long)b * N_ + n;
  }

  #pragma unroll
  for (int k0 = 0; k0 < 256; k0 += 32) {
    const int kk = k0 + kq;
    bf16x8 af[4], bfr[4];
    #pragma unroll
    for (int i = 0; i < 4; ++i) af[i] = *(const bf16x8*)(ap[i] + k0);
    if (kk < 240) {
      #pragma unroll
      for (int j = 0; j < 4; ++j) {
        const float* s;
        if (gmode == 0) {
          int soff;
          if (kk < 16)       soff = h * 16 + kk;
          else if (kk < 48)  soff = 64  + h * 32  + (kk - 16);
          else if (kk < 112) soff = 192 + h * 64  + (kk - 48);
          else               soff = 448 + h * 128 + (kk - 112);
          s = emb_all + rbn[j] * 960 + soff;
        } else {
          if (kk < 16)       s = e1 + rbn[j] * 64  + h * 16  + kk;
          else if (kk < 48)  s = e2 + rbn[j] * 128 + h * 32  + (kk - 16);
          else if (kk < 112) s = e3 + rbn[j] * 256 + h * 64  + (kk - 48);
          else               s = e4 + rbn[j] * 512 + h * 128 + (kk - 112);
        }
        bfr[j] = cvt8b(*(const float4*)s, *(const float4*)(s + 4));
      }
    } else {
      #pragma unroll
      for (int j = 0; j < 4; ++j) bfr[j] = (bf16x8)(short)0;
    }
    #pragma unroll
    for (int i = 0; i < 4; ++i)
      #pragma unroll
      for (int j = 0; j < 4; ++j)
        acc[i][j] = __builtin_amdgcn_mfma_f32_16x16x32_bf16(af[i], bfr[j], acc[i][j], 0, 0, 0);
  }

  const int quad = l >> 4, lc = l & 15;
  #pragma unroll
  for (int i = 0; i < 4; ++i) {
    #pragma unroll
    for (int r = 0; r < 4; ++r) {
      int row = m0 + wy * 64 + i * 16 + quad * 4 + r;
      if (row >= M) continue;
      ushort* Cr = C + (long)row * ldc;
      #pragma unroll
      for (int j = 0; j < 4; ++j) {
        int col = n0 + wx * 64 + j * 16 + lc;
        Cr[col] = f2b(acc[i][j][r]);
      }
    }
  }
}

// ---------------------------------------------------------------------------
// proj_gw_direct: A = fp32 gather (heads from emb_all, direct), B = weight
// bf16 (direct, row-clamped vs Nn). C bf16 [1024][Npad], cols zero-padded.
// ---------------------------------------------------------------------------
__device__ __forceinline__ void proj_gw_direct(
    const float* __restrict__ emb_all, int b, int h,
    const ushort* __restrict__ Bw, int Nn, int Npad,
    ushort* __restrict__ C, long ldc, int m0, int n0)
{
  const int tid = threadIdx.x;
  const int l = tid & 63, w = tid >> 6;
  const int wy = w >> 1, wx = w & 1;
  const int kq = (l >> 4) * 8;

  f32x4 acc[4][4];
  #pragma unroll
  for (int i = 0; i < 4; ++i)
    #pragma unroll
    for (int j = 0; j < 4; ++j) acc[i][j] = (f32x4)0.f;

  long ran[4];
  #pragma unroll
  for (int i = 0; i < 4; ++i) {
    int m = m0 + wy * 64 + i * 16 + (l & 15);
    ran[i] = (long)b * N_ + m;
  }
  const ushort* bp[4];
  #pragma unroll
  for (int j = 0; j < 4; ++j) {
    int r = n0 + wx * 64 + j * 16 + (l & 15);
    r = r < Nn ? r : Nn - 1;
    bp[j] = Bw + (long)r * 256 + kq;
  }

  #pragma unroll
  for (int k0 = 0; k0 < 256; k0 += 32) {
    const int kk = k0 + kq;
    bf16x8 af[4], bfr[4];
    #pragma unroll
    for (int j = 0; j < 4; ++j) bfr[j] = *(const bf16x8*)(bp[j] + k0);
    if (kk < 240) {
      int soff;
      if (kk < 16)       soff = h * 16 + kk;
      else if (kk < 48)  soff = 64  + h * 32  + (kk - 16);
      else if (kk < 112) soff = 192 + h * 64  + (kk - 48);
      else               soff = 448 + h * 128 + (kk - 112);
      #pragma unroll
      for (int i = 0; i < 4; ++i) {
        const float* s = emb_all + ran[i] * 960 + soff;
        af[i] = cvt8b(*(const float4*)s, *(const float4*)(s + 4));
      }
    } else {
      #pragma unroll
      for (int i = 0; i < 4; ++i) af[i] = (bf16x8)(short)0;
    }
    #pragma unroll
    for (int i = 0; i < 4; ++i)
      #pragma unroll
      for (int j = 0; j < 4; ++j)
        acc[i][j] = __builtin_amdgcn_mfma_f32_16x16x32_bf16(af[i], bfr[j], acc[i][j], 0, 0, 0);
  }

  const int quad = l >> 4, lc = l & 15;
  #pragma unroll
  for (int i = 0; i < 4; ++i) {
    #pragma unroll
    for (int r = 0; r < 4; ++r) {
      int row = m0 + wy * 64 + i * 16 + quad * 4 + r;
      ushort* Cr = C + (long)row * ldc;
      #pragma unroll
      for (int j = 0; j < 4; ++j) {
        int col = n0 + wx * 64 + j * 16 + lc;
        if (col < Nn) Cr[col] = f2b(acc[i][j][r]);
        else if (col < Npad) Cr[col] = 0;
      }
    }
  }
}

// ---------------------------------------------------------------------------
// mfma_proj v3: barrier-free direct-fragment K/V/Q projections.
// ---------------------------------------------------------------------------
__global__ __launch_bounds__(256) void mfma_proj(
    const float* __restrict__ emb_all,
    const float* __restrict__ e1, const float* __restrict__ e2,
    const float* __restrict__ e3, const float* __restrict__ e4,
    const ushort* __restrict__ Wk_b, const ushort* __restrict__ Wv_b,
    const ushort* __restrict__ Wq_bd,
    ushort* __restrict__ Kh_T, ushort* __restrict__ Vh, ushort* __restrict__ Q_T)
{
  const int bx = blockIdx.x;

  if (bx < 1024) {
    const int bh = bx >> 4, t = bx & 15;
    const int b = bh >> 2, h = bh & 3;
    proj_wg_direct(Wk_b, 240,
                   emb_all, e1, e2, e3, e4, 0, b, h,
                   Kh_T + (long)bh * 240 * 1024, 1024,
                   (t >> 3) * 128, (t & 7) * 128);
  } else if (bx < 2048) {
    const int local = bx - 1024;
    const int bh = local >> 4, t = local & 15;
    const int b = bh >> 2, h = bh & 3;
    proj_gw_direct(emb_all, b, h,
                   Wv_b, 240, 256,
                   Vh + (long)bh * 1024 * 256, 256,
                   (t >> 1) * 128, (t & 1) * 128);
  } else {
    const int local = bx - 2048;
    const int bh = local >> 4, t = local & 15;
    const int b = bh >> 2, h = bh & 3;
    proj_wg_direct(Wq_bd + h * 61440, 240,
                   emb_all, e1, e2, e3, e4, 1, b, h,
                   Q_T + (long)bh * 240 * 1024, 1024,
                   (t >> 3) * 128, (t & 7) * 128);
  }
}

// ---------------------------------------------------------------------------
// fused_sm: scores + InstanceNorm + softmax -> P, one block per (scale, bh).
// ---------------------------------------------------------------------------
__global__ __launch_bounds__(512) void fused_sm(const ushort* __restrict__ Q_T,
                                                const ushort* __restrict__ Kh_T,
                                                ushort* __restrict__ P,
                                                float alpha) {
  const int sidx = blockIdx.x, bh = blockIdx.y;
  const int dss[4]   = {16, 32, 64, 128};
  const int doffs[4] = {0, 16, 48, 112};
  const int ds = dss[sidx], doff = doffs[sidx];

  const int tid = threadIdx.x;
  const int l = tid & 63, w = tid >> 6;   // 8 waves
  const int wy = w >> 2, wx = w & 3;      // 2 x 4

  __shared__ __align__(16) ushort As[128 * 32];
  __shared__ __align__(16) ushort Bs[256 * 32];
  __shared__ float red[2][2][64][4];
  __shared__ float wred[2][8];

  f32x4 acc[4][4];
  #pragma unroll
  for (int i = 0; i < 4; ++i)
    #pragma unroll
    for (int j = 0; j < 4; ++j) acc[i][j] = (f32x4)0.f;

  const int srow = tid >> 2;              // 0..127
  const int skc  = (tid & 3) * 8;
  const long qbase = (long)bh * 240 * 1024;
  int qa = doff + (srow < ds ? srow : ds - 1);
  const ushort* a0 = Q_T + qbase + (long)qa * 1024 + skc;
  int kb1 = (srow + 128) < 240 ? (srow + 128) : 239;
  const ushort* b0 = Kh_T + qbase + (long)srow * 1024 + skc;
  const ushort* b1 = Kh_T + qbase + (long)kb1 * 1024 + skc;
  ushort* lA0 = As + srow * 32 + skc;
  ushort* lB0 = Bs + srow * 32 + skc;
  ushort* lB1 = Bs + (srow + 128) * 32 + skc;

  const ushort* arp = As + (wy * 64 + (l & 15)) * 32 + (l >> 4) * 8;
  const ushort* brp = Bs + (wx * 64 + (l & 15)) * 32 + (l >> 4) * 8;

  for (int k0 = 0; k0 < 1024; k0 += 32) {
    __syncthreads();
    gload16(a0 + k0, lA0);
    gload16(b0 + k0, lB0);
    gload16(b1 + k0, lB1);
    __syncthreads();
    bf16x8 af[4], bfr[4];
    #pragma unroll
    for (int i = 0; i < 4; ++i) af[i]  = *(const bf16x8*)(arp + i * 512);
    #pragma unroll
    for (int j = 0; j < 4; ++j) bfr[j] = *(const bf16x8*)(brp + j * 512);
    #pragma unroll
    for (int i = 0; i < 4; ++i)
      #pragma unroll
      for (int j = 0; j < 4; ++j)
        acc[i][j] = __builtin_amdgcn_mfma_f32_16x16x32_bf16(af[i], bfr[j], acc[i][j], 0, 0, 0);
  }

  const int quad = l >> 4, lc = l & 15;

  float s1 = 0.f, s2 = 0.f;
  #pragma unroll
  for (int i = 0; i < 4; ++i) {
    #pragma unroll
    for (int j = 0; j < 4; ++j) {
      const int col = wx * 64 + j * 16 + lc;
      #pragma unroll
      for (int r = 0; r < 4; ++r) {
        const int rl = wy * 64 + i * 16 + quad * 4 + r;
        float v = acc[i][j][r] * alpha;
        acc[i][j][r] = v;
        if (rl < ds && col < 240) { s1 += v; s2 += v * v; }
      }
    }
  }
  #pragma unroll
  for (int o = 32; o > 0; o >>= 1) { s1 += __shfl_xor(s1, o); s2 += __shfl_xor(s2, o); }
  if (l == 0) { wred[0][w] = s1; wred[1][w] = s2; }
  __syncthreads();
  float ts = 0.f, ts2 = 0.f;
  #pragma unroll
  for (int ww = 0; ww < 8; ++ww) { ts += wred[0][ww]; ts2 += wred[1][ww]; }
  const float cnt = (float)(ds * 240);
  const float mean = ts / cnt;
  const float var = ts2 / cnt - mean * mean;
  const float rstd = rsqrtf(var + 1e-5f);

  float rmax[4][4];
  #pragma unroll
  for (int i = 0; i < 4; ++i) {
    #pragma unroll
    for (int r = 0; r < 4; ++r) {
      float m = -1e30f;
      #pragma unroll
      for (int j = 0; j < 4; ++j) {
        const int col = wx * 64 + j * 16 + lc;
        float z = (acc[i][j][r] - mean) * rstd;
        acc[i][j][r] = z;
        if (col < 240) m = fmaxf(m, z);
      }
      m = fmaxf(m, __shfl_xor(m, 1));
      m = fmaxf(m, __shfl_xor(m, 2));
      m = fmaxf(m, __shfl_xor(m, 4));
      m = fmaxf(m, __shfl_xor(m, 8));
      rmax[i][r] = m;
    }
  }
  if (lc == 0) {
    #pragma unroll
    for (int i = 0; i < 4; ++i)
      #pragma unroll
      for (int r = 0; r < 4; ++r)
        red[0][wy][i * 16 + quad * 4 + r][wx] = rmax[i][r];
  }
  __syncthreads();
  #pragma unroll
  for (int i = 0; i < 4; ++i) {
    #pragma unroll
    for (int r = 0; r < 4; ++r) {
      const int rl = i * 16 + quad * 4 + r;
      float m = red[0][wy][rl][0];
      m = fmaxf(m, red[0][wy][rl][1]);
      m = fmaxf(m, red[0][wy][rl][2]);
      m = fmaxf(m, red[0][wy][rl][3]);
      rmax[i][r] = m;
    }
  }

  float rsum[4][4];
  #pragma unroll
  for (int i = 0; i < 4; ++i) {
    #pragma unroll
    for (int r = 0; r < 4; ++r) {
      float sacc = 0.f;
      #pragma unroll
      for (int j = 0; j < 4; ++j) {
        const int col = wx * 64 + j * 16 + lc;
        float e = (col < 240) ? __expf(acc[i][j][r] - rmax[i][r]) : 0.f;
        acc[i][j][r] = e;
        sacc += e;
      }
      sacc += __shfl_xor(sacc, 1);
      sacc += __shfl_xor(sacc, 2);
      sacc += __shfl_xor(sacc, 4);
      sacc += __shfl_xor(sacc, 8);
      rsum[i][r] = sacc;
    }
  }
  if (lc == 0) {
    #pragma unroll
    for (int i = 0; i < 4; ++i)
      #pragma unroll
      for (int r = 0; r < 4; ++r)
        red[1][wy][i * 16 + quad * 4 + r][wx] = rsum[i][r];
  }
  __syncthreads();

  #pragma unroll
  for (int i = 0; i < 4; ++i) {
    #pragma unroll
    for (int r = 0; r < 4; ++r) {
      const int rl = wy * 64 + i * 16 + quad * 4 + r;
      if (rl >= ds) continue;
      const int rli = i * 16 + quad * 4 + r;
      float tot = red[1][wy][rli][0] + red[1][wy][rli][1] +
                  red[1][wy][rli][2] + red[1][wy][rli][3];
      float inv = 1.f / tot;
      ushort* Pr = P + ((long)bh * 240 + doff + rl) * 256;
      #pragma unroll
      for (int j = 0; j < 4; ++j) {
        const int col = wx * 64 + j * 16 + lc;
        Pr[col] = (col < 240) ? f2b(acc[i][j][r] * inv) : (ushort)0;
      }
    }
  }
}

// ---------------------------------------------------------------------------
// mfma_ctx: fused ctx GEMM. A=Vh[bh] [1024,256], B=P_b[bh] [240,256], K=256.
// ---------------------------------------------------------------------------
__global__ __launch_bounds__(256) void mfma_ctx(const ushort* __restrict__ V,
                                                const ushort* __restrict__ P,
                                                ushort* __restrict__ ctx2) {
  const int h = blockIdx.y, b = blockIdx.z;
  const ushort* A  = V + (((long)b * H_ + h) * 1024) * 256;
  const ushort* Bm = P + (((long)b * H_ + h) * 240) * 256;

  const int m0 = (blockIdx.x >> 1) * 128;
  const int n0 = (blockIdx.x & 1) * 128;
  const int tid = threadIdx.x;
  const int l = tid & 63, w = tid >> 6;
  const int wy = w >> 1, wx = w & 1;

  __shared__ __align__(16) ushort As[128 * 32];
  __shared__ __align__(16) ushort Bs[128 * 32];

  f32x4 acc[4][4];
  #pragma unroll
  for (int i = 0; i < 4; ++i)
    #pragma unroll
    for (int j = 0; j < 4; ++j) acc[i][j] = (f32x4)0.f;

  const int srow = tid >> 2;
  const int skc  = (tid & 3) * 8;
  int rb0 = n0 + srow;      rb0 = rb0 < 240 ? rb0 : 239;
  int rb1 = n0 + srow + 64; rb1 = rb1 < 240 ? rb1 : 239;
  const ushort* a0 = A  + (long)(m0 + srow) * 256 + skc;
  const ushort* a1 = A  + (long)(m0 + srow + 64) * 256 + skc;
  const ushort* b0 = Bm + (long)rb0 * 256 + skc;
  const ushort* b1 = Bm + (long)rb1 * 256 + skc;
  ushort* lA0 = As + srow * 32 + skc;
  ushort* lA1 = As + (srow + 64) * 32 + skc;
  ushort* lB0 = Bs + srow * 32 + skc;
  ushort* lB1 = Bs + (srow + 64) * 32 + skc;

  const ushort* arp = As + (wy * 64 + (l & 15)) * 32 + (l >> 4) * 8;
  const ushort* brp = Bs + (wx * 64 + (l & 15)) * 32 + (l >> 4) * 8;

  for (int k0 = 0; k0 < 256; k0 += 32) {
    __syncthreads();
    gload16(a0 + k0, lA0);
    gload16(a1 + k0, lA1);
    gload16(b0 + k0, lB0);
    gload16(b1 + k0, lB1);
    __syncthreads();
    bf16x8 af[4], bfr[4];
    #pragma unroll
    for (int i = 0; i < 4; ++i) af[i]  = *(const bf16x8*)(arp + i * 512);
    #pragma unroll
    for (int j = 0; j < 4; ++j) bfr[j] = *(const bf16x8*)(brp + j * 512);
    #pragma unroll
    for (int i = 0; i < 4; ++i)
      #pragma unroll
      for (int j = 0; j < 4; ++j)
        acc[i][j] = __builtin_amdgcn_mfma_f32_16x16x32_bf16(af[i], bfr[j], acc[i][j], 0, 0, 0);
  }

  const int quad = l >> 4, lc = l & 15;
  const int dss[4] = {16, 32, 64, 128};
  const int qf[4]  = {0, 16, 48, 112};
  const int cf[4]  = {0, 64, 192, 448};
  #pragma unroll
  for (int i = 0; i < 4; ++i) {
    #pragma unroll
    for (int r = 0; r < 4; ++r) {
      int row = m0 + wy * 64 + i * 16 + quad * 4 + r;
      ushort* Cr = ctx2 + ((long)b * N_ + row) * 960;
      #pragma unroll
      for (int j = 0; j < 4; ++j) {
        int col = n0 + wx * 64 + j * 16 + lc;
        if (col < 240) {
          int s = col < 16 ? 0 : col < 48 ? 1 : col < 112 ? 2 : 3;
          int chan = cf[s] + h * dss[s] + (col - qf[s]);
          Cr[chan] = f2b(acc[i][j][r]);
        }
      }
    }
  }
}

// ---------------------------------------------------------------------------
// mfma_oproj: grouped out-projection, one dispatch for all 4 scales.
// ---------------------------------------------------------------------------
__global__ __launch_bounds__(256) void mfma_oproj(const ushort* __restrict__ ctx2,
                                                  const ushort* __restrict__ Wo_b,
                                                  float* __restrict__ out) {
  const int bx = blockIdx.x;
  int s = bx < 128 ? 0 : bx < 256 ? 1 : bx < 512 ? 2 : 3;
  const int sbase[4] = {0, 128, 256, 512};
  const int cs_[4]   = {64, 128, 256, 512};
  const int coff_[4] = {0, 64, 192, 448};
  const int wo_[4]   = {0, 4096, 20480, 86016};
  const long oo_[4]  = {0, 1048576, 3145728, 7340032};
  const int c = cs_[s];
  const int nt = (c + 127) >> 7;
  const int local = bx - sbase[s];
  const int m0 = (local / nt) * 128;
  const int n0 = (local % nt) * 128;

  const ushort* A  = ctx2 + coff_[s];
  const ushort* Bm = Wo_b + wo_[s];
  float* C = out + oo_[s];
  const int K = c, Nn = c;

  const int tid = threadIdx.x;
  const int l = tid & 63, w = tid >> 6;
  const int wy = w >> 1, wx = w & 1;

  __shared__ __align__(16) ushort As[128 * 32];
  __shared__ __align__(16) ushort Bs[128 * 32];

  f32x4 acc[4][4];
  #pragma unroll
  for (int i = 0; i < 4; ++i)
    #pragma unroll
    for (int j = 0; j < 4; ++j) acc[i][j] = (f32x4)0.f;

  const int srow = tid >> 2;
  const int skc  = (tid & 3) * 8;
  int rb0 = n0 + srow;      rb0 = rb0 < Nn ? rb0 : Nn - 1;
  int rb1 = n0 + srow + 64; rb1 = rb1 < Nn ? rb1 : Nn - 1;
  const ushort* a0 = A  + (long)(m0 + srow) * 960 + skc;
  const ushort* a1 = A  + (long)(m0 + srow + 64) * 960 + skc;
  const ushort* b0 = Bm + (long)rb0 * c + skc;
  const ushort* b1 = Bm + (long)rb1 * c + skc;
  ushort* lA0 = As + srow * 32 + skc;
  ushort* lA1 = As + (srow + 64) * 32 + skc;
  ushort* lB0 = Bs + srow * 32 + skc;
  ushort* lB1 = Bs + (srow + 64) * 32 + skc;

  const ushort* arp = As + (wy * 64 + (l & 15)) * 32 + (l >> 4) * 8;
  const ushort* brp = Bs + (wx * 64 + (l & 15)) * 32 + (l >> 4) * 8;

  for (int k0 = 0; k0 < K; k0 += 32) {
    __syncthreads();
    gload16(a0 + k0, lA0);
    gload16(a1 + k0, lA1);
    gload16(b0 + k0, lB0);
    gload16(b1 + k0, lB1);
    __syncthreads();
    bf16x8 af[4], bfr[4];
    #pragma unroll
    for (int i = 0; i < 4; ++i) af[i]  = *(const bf16x8*)(arp + i * 512);
    #pragma unroll
    for (int j = 0; j < 4; ++j) bfr[j] = *(const bf16x8*)(brp + j * 512);
    #pragma unroll
    for (int i = 0; i < 4; ++i)
      #pragma unroll
      for (int j = 0; j < 4; ++j)
        acc[i][j] = __builtin_amdgcn_mfma_f32_16x16x32_bf16(af[i], bfr[j], acc[i][j], 0, 0, 0);
  }

  const int quad = l >> 4, lc = l & 15;
  #pragma unroll
  for (int i = 0; i < 4; ++i) {
    #pragma unroll
    for (int r = 0; r < 4; ++r) {
      int row = m0 + wy * 64 + i * 16 + quad * 4 + r;
      float* Cr = C + (long)row * c;
      #pragma unroll
      for (int j = 0; j < 4; ++j) {
        int col = n0 + wx * 64 + j * 16 + lc;
        if (col < Nn) Cr[col] = acc[i][j][r];
      }
    }
  }
}

// ---------------------------------------------------------------------------
// launch
// ---------------------------------------------------------------------------
extern "C" void kernel_launch(void* const* d_in, const int* in_sizes, int n_in,
                              void* d_out, int out_size, void* d_ws, size_t ws_size,
                              hipStream_t stream) {
  const float* emb[4] = {(const float*)d_in[0], (const float*)d_in[1],
                         (const float*)d_in[2], (const float*)d_in[3]};
  const float* emb_all = (const float*)d_in[4];
  const float* Wq[4] = {(const float*)d_in[5], (const float*)d_in[6],
                        (const float*)d_in[7], (const float*)d_in[8]};
  const float* Wk = (const float*)d_in[9];
  const float* Wv = (const float*)d_in[10];
  const float* Wo[4] = {(const float*)d_in[11], (const float*)d_in[12],
                        (const float*)d_in[13], (const float*)d_in[14]};
  float* out = (float*)d_out;

  ushort* wsb     = (ushort*)d_ws;
  ushort* ctx2    = wsb;               // [B,N,960]
  ushort* P_b     = wsb + 16777216;    // [64,240,256]
  ushort* Q_T     = wsb + 33554432;    // [B,H,240,1024]
  ushort* Kh_T    = wsb + 49283072;    // [B,H,240,1024]
  ushort* Vh      = wsb + 65011712;    // [B,H,1024,256]
  ushort* wts     = wsb + 81788928;    // 716800: Wk_b|Wv_b|Wq_bd|Wo_b
  ushort* Wk_b  = wts;
  ushort* Wv_b  = wts + 61440;
  ushort* Wq_bd = wts + 122880;
  ushort* Wo_b  = wts + 368640;

  const float alpha_s = 1.0f / sqrtf(960.0f);

  conv_weights<<<dim3(2800), 256, 0, stream>>>(Wk, Wv, Wq[0], Wq[1], Wq[2], Wq[3],
                                               Wo[0], Wo[1], Wo[2], Wo[3], wts);

  // merged K/V/Q projections — barrier-free direct-fragment cores
  mfma_proj<<<dim3(3072), 256, 0, stream>>>(emb_all, emb[0], emb[1], emb[2], emb[3],
                                            Wk_b, Wv_b, Wq_bd, Kh_T, Vh, Q_T);

  // fused scores + InstanceNorm + softmax -> P
  fused_sm<<<dim3(4, 64), 512, 0, stream>>>(Q_T, Kh_T, P_b, alpha_s);

  // fused ctx
  mfma_ctx<<<dim3(16, H_, B_), 256, 0, stream>>>(Vh, P_b, ctx2);

  // grouped out-proj
  mfma_oproj<<<dim3(1024), 256, 0, stream>>>(ctx2, Wo_b, out);
}

// Round 9
// 343.175 us; speedup vs baseline: 1.1908x; 1.1908x over previous
//
#include <hip/hip_runtime.h>
#include <hip/hip_bf16.h>
#include <math.h>

#define B_   16
#define N_   1024
#define H_   4
#define D240 240

typedef unsigned short ushort;
typedef __attribute__((ext_vector_type(8))) short bf16x8;
typedef __attribute__((ext_vector_type(8))) unsigned short u16x8;
typedef __attribute__((ext_vector_type(4))) float f32x4;

__device__ __forceinline__ ushort f2b(float v) {
  __hip_bfloat16 h = __float2bfloat16(v);
  return *reinterpret_cast<ushort*>(&h);
}

__device__ __forceinline__ u16x8 cvt8(float4 a, float4 b) {
  u16x8 w;
  w[0] = f2b(a.x); w[1] = f2b(a.y); w[2] = f2b(a.z); w[3] = f2b(a.w);
  w[4] = f2b(b.x); w[5] = f2b(b.y); w[6] = f2b(b.z); w[7] = f2b(b.w);
  return w;
}

__device__ __forceinline__ void gload16(const void* g, void* s) {
  __builtin_amdgcn_global_load_lds((const __attribute__((address_space(1))) void*)g,
                                   (__attribute__((address_space(3))) void*)s, 16, 0, 0);
}

// Gather address helpers: regrouped-head channel k -> fp32 source pointer.
__device__ __forceinline__ const float* heads_src(const float* __restrict__ emb_all,
                                                  int b, int n, int h, int k) {
  int soff;
  if (k < 16)       soff = h * 16 + k;
  else if (k < 48)  soff = 64  + h * 32  + (k - 16);
  else if (k < 112) soff = 192 + h * 64  + (k - 48);
  else              soff = 448 + h * 128 + (k - 112);
  return emb_all + ((long)b * N_ + n) * 960 + soff;
}

__device__ __forceinline__ const float* emb_src(const float* __restrict__ e1,
                                                const float* __restrict__ e2,
                                                const float* __restrict__ e3,
                                                const float* __restrict__ e4,
                                                int b, int n, int h, int k, int* stride) {
  if (k < 16)  { *stride = 64;  return e1 + ((long)b * N_ + n) * 64  + h * 16  + k; }
  if (k < 48)  { *stride = 128; return e2 + ((long)b * N_ + n) * 128 + h * 32  + (k - 16); }
  if (k < 112) { *stride = 256; return e3 + ((long)b * N_ + n) * 256 + h * 64  + (k - 48); }
  *stride = 512; return e4 + ((long)b * N_ + n) * 512 + h * 128 + (k - 112);
}

// ---------------------------------------------------------------------------
// conv_weights: Wk_b | Wv_b | Wq_bd (block-diag per head) | Wo_b (col-permuted)
// ---------------------------------------------------------------------------
__global__ __launch_bounds__(256) void conv_weights(
    const float* __restrict__ Wk, const float* __restrict__ Wv,
    const float* __restrict__ q1, const float* __restrict__ q2,
    const float* __restrict__ q3, const float* __restrict__ q4,
    const float* __restrict__ o1, const float* __restrict__ o2,
    const float* __restrict__ o3, const float* __restrict__ o4,
    ushort* __restrict__ wts) {
  long i = (long)blockIdx.x * 256 + threadIdx.x;
  if (i >= 716800) return;
  float v = 0.f;
  if (i < 122880) {
    const float* src = (i < 61440) ? Wk : Wv;
    long j = (i < 61440) ? i : i - 61440;
    int r = j / 256, k = j % 256;
    if (k < 240) v = src[(long)r * 240 + k];
  } else if (i < 368640) {
    long j = i - 122880;
    int h = j / 61440; int rem = j % 61440;
    int r = rem / 256, k = rem % 256;
    int s = r < 16 ? 0 : r < 48 ? 1 : r < 112 ? 2 : 3;
    const int dss[4] = {16, 32, 64, 128};
    const int qf[4]  = {0, 16, 48, 112};
    const float* qs[4] = {q1, q2, q3, q4};
    int d = dss[s], off = qf[s];
    if (k >= off && k < off + d)
      v = qs[s][((long)(h * d + (r - off))) * d + (k - off)];
  } else {
    long j = i - 368640;
    int s = j < 4096 ? 0 : j < 20480 ? 1 : j < 86016 ? 2 : 3;
    const long base[4] = {0, 4096, 20480, 86016};
    const int cs[4] = {64, 128, 256, 512};
    const float* os[4] = {o1, o2, o3, o4};
    long rem = j - base[s];
    int c = cs[s], d = c >> 2;
    int e = rem / c, kk = rem % c;
    v = os[s][(long)e * c + (kk % d) * 4 + kk / d];
  }
  wts[i] = f2b(v);
}

// ---------------------------------------------------------------------------
// core_w_g (R5 staged version — best measured): A = weight bf16 (gload16,
// row-clamped vs M), B = fp32 GATHER converted in regs and ds_write'd.
// ---------------------------------------------------------------------------
__device__ __forceinline__ void core_w_g(
    ushort* As, ushort* Bs,
    const ushort* __restrict__ Aw, long lda, int M,
    const float* __restrict__ emb_all,
    const float* __restrict__ e1, const float* __restrict__ e2,
    const float* __restrict__ e3, const float* __restrict__ e4,
    int gmode, int b, int h,
    ushort* __restrict__ C, long ldc, int m0, int n0, int K)
{
  const int tid = threadIdx.x;
  const int l = tid & 63, w = tid >> 6;
  const int wy = w >> 1, wx = w & 1;

  f32x4 acc[4][4];
  #pragma unroll
  for (int i = 0; i < 4; ++i)
    #pragma unroll
    for (int j = 0; j < 4; ++j) acc[i][j] = (f32x4)0.f;

  const int srow = tid >> 2;
  const int skc  = (tid & 3) * 8;
  int ra0 = m0 + srow;      ra0 = ra0 < M ? ra0 : M - 1;
  int ra1 = m0 + srow + 64; ra1 = ra1 < M ? ra1 : M - 1;
  const ushort* a0 = Aw + (long)ra0 * lda + skc;
  const ushort* a1 = Aw + (long)ra1 * lda + skc;
  ushort* lA0 = As + srow * 32 + skc;
  ushort* lA1 = As + (srow + 64) * 32 + skc;
  ushort* lB0 = Bs + srow * 32 + skc;
  ushort* lB1 = Bs + (srow + 64) * 32 + skc;
  const int nrow = n0 + srow;

  const ushort* arp = As + (wy * 64 + (l & 15)) * 32 + (l >> 4) * 8;
  const ushort* brp = Bs + (wx * 64 + (l & 15)) * 32 + (l >> 4) * 8;

  for (int k0 = 0; k0 < K; k0 += 32) {
    __syncthreads();
    gload16(a0 + k0, lA0);
    gload16(a1 + k0, lA1);
    const int k = k0 + skc;
    u16x8 w0, w1;
    if (k < 240) {
      const float* s0; int stride;
      if (gmode == 0) { stride = 960; s0 = heads_src(emb_all, b, nrow, h, k); }
      else            { s0 = emb_src(e1, e2, e3, e4, b, nrow, h, k, &stride); }
      const float* s1 = s0 + (long)64 * stride;
      float4 p0 = *(const float4*)s0, p1 = *(const float4*)(s0 + 4);
      float4 q0 = *(const float4*)s1, q1 = *(const float4*)(s1 + 4);
      w0 = cvt8(p0, p1); w1 = cvt8(q0, q1);
    } else {
      w0 = (u16x8)0; w1 = (u16x8)0;
    }
    *(u16x8*)lB0 = w0;
    *(u16x8*)lB1 = w1;
    __syncthreads();
    bf16x8 af[4], bfr[4];
    #pragma unroll
    for (int i = 0; i < 4; ++i) af[i]  = *(const bf16x8*)(arp + i * 512);
    #pragma unroll
    for (int j = 0; j < 4; ++j) bfr[j] = *(const bf16x8*)(brp + j * 512);
    #pragma unroll
    for (int i = 0; i < 4; ++i)
      #pragma unroll
      for (int j = 0; j < 4; ++j)
        acc[i][j] = __builtin_amdgcn_mfma_f32_16x16x32_bf16(af[i], bfr[j], acc[i][j], 0, 0, 0);
  }

  const int quad = l >> 4, lc = l & 15;
  #pragma unroll
  for (int i = 0; i < 4; ++i) {
    #pragma unroll
    for (int r = 0; r < 4; ++r) {
      int row = m0 + wy * 64 + i * 16 + quad * 4 + r;
      if (row >= M) continue;
      ushort* Cr = C + (long)row * ldc;
      #pragma unroll
      for (int j = 0; j < 4; ++j) {
        int col = n0 + wx * 64 + j * 16 + lc;
        Cr[col] = f2b(acc[i][j][r]);
      }
    }
  }
}

// ---------------------------------------------------------------------------
// core_g_w (R5 staged version): A = fp32 gather, B = weight bf16 (gload16).
// ---------------------------------------------------------------------------
__device__ __forceinline__ void core_g_w(
    ushort* As, ushort* Bs,
    const float* __restrict__ emb_all, int b, int h,
    const ushort* __restrict__ Bw, long ldb, int Nn, int Npad,
    ushort* __restrict__ C, long ldc, int m0, int n0, int K)
{
  const int tid = threadIdx.x;
  const int l = tid & 63, w = tid >> 6;
  const int wy = w >> 1, wx = w & 1;

  f32x4 acc[4][4];
  #pragma unroll
  for (int i = 0; i < 4; ++i)
    #pragma unroll
    for (int j = 0; j < 4; ++j) acc[i][j] = (f32x4)0.f;

  const int srow = tid >> 2;
  const int skc  = (tid & 3) * 8;
  int rb0 = n0 + srow;      rb0 = rb0 < Nn ? rb0 : Nn - 1;
  int rb1 = n0 + srow + 64; rb1 = rb1 < Nn ? rb1 : Nn - 1;
  const ushort* b0 = Bw + (long)rb0 * ldb + skc;
  const ushort* b1 = Bw + (long)rb1 * ldb + skc;
  ushort* lA0 = As + srow * 32 + skc;
  ushort* lA1 = As + (srow + 64) * 32 + skc;
  ushort* lB0 = Bs + srow * 32 + skc;
  ushort* lB1 = Bs + (srow + 64) * 32 + skc;
  const int mrow = m0 + srow;

  const ushort* arp = As + (wy * 64 + (l & 15)) * 32 + (l >> 4) * 8;
  const ushort* brp = Bs + (wx * 64 + (l & 15)) * 32 + (l >> 4) * 8;

  for (int k0 = 0; k0 < K; k0 += 32) {
    __syncthreads();
    gload16(b0 + k0, lB0);
    gload16(b1 + k0, lB1);
    const int k = k0 + skc;
    u16x8 w0, w1;
    if (k < 240) {
      const float* s0 = heads_src(emb_all, b, mrow, h, k);
      const float* s1 = s0 + (long)64 * 960;
      float4 p0 = *(const float4*)s0, p1 = *(const float4*)(s0 + 4);
      float4 q0 = *(const float4*)s1, q1 = *(const float4*)(s1 + 4);
      w0 = cvt8(p0, p1); w1 = cvt8(q0, q1);
    } else {
      w0 = (u16x8)0; w1 = (u16x8)0;
    }
    *(u16x8*)lA0 = w0;
    *(u16x8*)lA1 = w1;
    __syncthreads();
    bf16x8 af[4], bfr[4];
    #pragma unroll
    for (int i = 0; i < 4; ++i) af[i]  = *(const bf16x8*)(arp + i * 512);
    #pragma unroll
    for (int j = 0; j < 4; ++j) bfr[j] = *(const bf16x8*)(brp + j * 512);
    #pragma unroll
    for (int i = 0; i < 4; ++i)
      #pragma unroll
      for (int j = 0; j < 4; ++j)
        acc[i][j] = __builtin_amdgcn_mfma_f32_16x16x32_bf16(af[i], bfr[j], acc[i][j], 0, 0, 0);
  }

  const int quad = l >> 4, lc = l & 15;
  #pragma unroll
  for (int i = 0; i < 4; ++i) {
    #pragma unroll
    for (int r = 0; r < 4; ++r) {
      int row = m0 + wy * 64 + i * 16 + quad * 4 + r;
      ushort* Cr = C + (long)row * ldc;
      #pragma unroll
      for (int j = 0; j < 4; ++j) {
        int col = n0 + wx * 64 + j * 16 + lc;
        if (col < Nn) Cr[col] = f2b(acc[i][j][r]);
        else if (col < Npad) Cr[col] = 0;
      }
    }
  }
}

// ---------------------------------------------------------------------------
// mfma_proj (R5 staged): K/V/Q projections reading fp32 sources directly.
// ---------------------------------------------------------------------------
__global__ __launch_bounds__(256) void mfma_proj(
    const float* __restrict__ emb_all,
    const float* __restrict__ e1, const float* __restrict__ e2,
    const float* __restrict__ e3, const float* __restrict__ e4,
    const ushort* __restrict__ Wk_b, const ushort* __restrict__ Wv_b,
    const ushort* __restrict__ Wq_bd,
    ushort* __restrict__ Kh_T, ushort* __restrict__ Vh, ushort* __restrict__ Q_T)
{
  __shared__ __align__(16) ushort As[128 * 32];
  __shared__ __align__(16) ushort Bs[128 * 32];
  const int bx = blockIdx.x;

  if (bx < 1024) {
    const int bh = bx >> 4, t = bx & 15;
    const int b = bh >> 2, h = bh & 3;
    core_w_g(As, Bs, Wk_b, 256, 240,
             emb_all, e1, e2, e3, e4, 0, b, h,
             Kh_T + (long)bh * 240 * 1024, 1024,
             (t >> 3) * 128, (t & 7) * 128, 256);
  } else if (bx < 2048) {
    const int local = bx - 1024;
    const int bh = local >> 4, t = local & 15;
    const int b = bh >> 2, h = bh & 3;
    core_g_w(As, Bs, emb_all, b, h,
             Wv_b, 256, 240, 256,
             Vh + (long)bh * 1024 * 256, 256,
             (t >> 1) * 128, (t & 1) * 128, 256);
  } else {
    const int local = bx - 2048;
    const int bh = local >> 4, t = local & 15;
    const int b = bh >> 2, h = bh & 3;
    core_w_g(As, Bs, Wq_bd + h * 61440, 256, 240,
             emb_all, e1, e2, e3, e4, 1, b, h,
             Q_T + (long)bh * 240 * 1024, 1024,
             (t >> 3) * 128, (t & 7) * 128, 256);
  }
}

// ---------------------------------------------------------------------------
// fused_sm: scores + InstanceNorm + softmax -> P, one block per (scale, bh).
// ---------------------------------------------------------------------------
__global__ __launch_bounds__(512) void fused_sm(const ushort* __restrict__ Q_T,
                                                const ushort* __restrict__ Kh_T,
                                                ushort* __restrict__ P,
                                                float alpha) {
  const int sidx = blockIdx.x, bh = blockIdx.y;
  const int dss[4]   = {16, 32, 64, 128};
  const int doffs[4] = {0, 16, 48, 112};
  const int ds = dss[sidx], doff = doffs[sidx];

  const int tid = threadIdx.x;
  const int l = tid & 63, w = tid >> 6;   // 8 waves
  const int wy = w >> 2, wx = w & 3;      // 2 x 4

  __shared__ __align__(16) ushort As[128 * 32];
  __shared__ __align__(16) ushort Bs[256 * 32];
  __shared__ float red[2][2][64][4];
  __shared__ float wred[2][8];

  f32x4 acc[4][4];
  #pragma unroll
  for (int i = 0; i < 4; ++i)
    #pragma unroll
    for (int j = 0; j < 4; ++j) acc[i][j] = (f32x4)0.f;

  const int srow = tid >> 2;              // 0..127
  const int skc  = (tid & 3) * 8;
  const long qbase = (long)bh * 240 * 1024;
  int qa = doff + (srow < ds ? srow : ds - 1);
  const ushort* a0 = Q_T + qbase + (long)qa * 1024 + skc;
  int kb1 = (srow + 128) < 240 ? (srow + 128) : 239;
  const ushort* b0 = Kh_T + qbase + (long)srow * 1024 + skc;
  const ushort* b1 = Kh_T + qbase + (long)kb1 * 1024 + skc;
  ushort* lA0 = As + srow * 32 + skc;
  ushort* lB0 = Bs + srow * 32 + skc;
  ushort* lB1 = Bs + (srow + 128) * 32 + skc;

  const ushort* arp = As + (wy * 64 + (l & 15)) * 32 + (l >> 4) * 8;
  const ushort* brp = Bs + (wx * 64 + (l & 15)) * 32 + (l >> 4) * 8;

  for (int k0 = 0; k0 < 1024; k0 += 32) {
    __syncthreads();
    gload16(a0 + k0, lA0);
    gload16(b0 + k0, lB0);
    gload16(b1 + k0, lB1);
    __syncthreads();
    bf16x8 af[4], bfr[4];
    #pragma unroll
    for (int i = 0; i < 4; ++i) af[i]  = *(const bf16x8*)(arp + i * 512);
    #pragma unroll
    for (int j = 0; j < 4; ++j) bfr[j] = *(const bf16x8*)(brp + j * 512);
    #pragma unroll
    for (int i = 0; i < 4; ++i)
      #pragma unroll
      for (int j = 0; j < 4; ++j)
        acc[i][j] = __builtin_amdgcn_mfma_f32_16x16x32_bf16(af[i], bfr[j], acc[i][j], 0, 0, 0);
  }

  const int quad = l >> 4, lc = l & 15;

  float s1 = 0.f, s2 = 0.f;
  #pragma unroll
  for (int i = 0; i < 4; ++i) {
    #pragma unroll
    for (int j = 0; j < 4; ++j) {
      const int col = wx * 64 + j * 16 + lc;
      #pragma unroll
      for (int r = 0; r < 4; ++r) {
        const int rl = wy * 64 + i * 16 + quad * 4 + r;
        float v = acc[i][j][r] * alpha;
        acc[i][j][r] = v;
        if (rl < ds && col < 240) { s1 += v; s2 += v * v; }
      }
    }
  }
  #pragma unroll
  for (int o = 32; o > 0; o >>= 1) { s1 += __shfl_xor(s1, o); s2 += __shfl_xor(s2, o); }
  if (l == 0) { wred[0][w] = s1; wred[1][w] = s2; }
  __syncthreads();
  float ts = 0.f, ts2 = 0.f;
  #pragma unroll
  for (int ww = 0; ww < 8; ++ww) { ts += wred[0][ww]; ts2 += wred[1][ww]; }
  const float cnt = (float)(ds * 240);
  const float mean = ts / cnt;
  const float var = ts2 / cnt - mean * mean;
  const float rstd = rsqrtf(var + 1e-5f);

  float rmax[4][4];
  #pragma unroll
  for (int i = 0; i < 4; ++i) {
    #pragma unroll
    for (int r = 0; r < 4; ++r) {
      float m = -1e30f;
      #pragma unroll
      for (int j = 0; j < 4; ++j) {
        const int col = wx * 64 + j * 16 + lc;
        float z = (acc[i][j][r] - mean) * rstd;
        acc[i][j][r] = z;
        if (col < 240) m = fmaxf(m, z);
      }
      m = fmaxf(m, __shfl_xor(m, 1));
      m = fmaxf(m, __shfl_xor(m, 2));
      m = fmaxf(m, __shfl_xor(m, 4));
      m = fmaxf(m, __shfl_xor(m, 8));
      rmax[i][r] = m;
    }
  }
  if (lc == 0) {
    #pragma unroll
    for (int i = 0; i < 4; ++i)
      #pragma unroll
      for (int r = 0; r < 4; ++r)
        red[0][wy][i * 16 + quad * 4 + r][wx] = rmax[i][r];
  }
  __syncthreads();
  #pragma unroll
  for (int i = 0; i < 4; ++i) {
    #pragma unroll
    for (int r = 0; r < 4; ++r) {
      const int rl = i * 16 + quad * 4 + r;
      float m = red[0][wy][rl][0];
      m = fmaxf(m, red[0][wy][rl][1]);
      m = fmaxf(m, red[0][wy][rl][2]);
      m = fmaxf(m, red[0][wy][rl][3]);
      rmax[i][r] = m;
    }
  }

  float rsum[4][4];
  #pragma unroll
  for (int i = 0; i < 4; ++i) {
    #pragma unroll
    for (int r = 0; r < 4; ++r) {
      float sacc = 0.f;
      #pragma unroll
      for (int j = 0; j < 4; ++j) {
        const int col = wx * 64 + j * 16 + lc;
        float e = (col < 240) ? __expf(acc[i][j][r] - rmax[i][r]) : 0.f;
        acc[i][j][r] = e;
        sacc += e;
      }
      sacc += __shfl_xor(sacc, 1);
      sacc += __shfl_xor(sacc, 2);
      sacc += __shfl_xor(sacc, 4);
      sacc += __shfl_xor(sacc, 8);
      rsum[i][r] = sacc;
    }
  }
  if (lc == 0) {
    #pragma unroll
    for (int i = 0; i < 4; ++i)
      #pragma unroll
      for (int r = 0; r < 4; ++r)
        red[1][wy][i * 16 + quad * 4 + r][wx] = rsum[i][r];
  }
  __syncthreads();

  #pragma unroll
  for (int i = 0; i < 4; ++i) {
    #pragma unroll
    for (int r = 0; r < 4; ++r) {
      const int rl = wy * 64 + i * 16 + quad * 4 + r;
      if (rl >= ds) continue;
      const int rli = i * 16 + quad * 4 + r;
      float tot = red[1][wy][rli][0] + red[1][wy][rli][1] +
                  red[1][wy][rli][2] + red[1][wy][rli][3];
      float inv = 1.f / tot;
      ushort* Pr = P + ((long)bh * 240 + doff + rl) * 256;
      #pragma unroll
      for (int j = 0; j < 4; ++j) {
        const int col = wx * 64 + j * 16 + lc;
        Pr[col] = (col < 240) ? f2b(acc[i][j][r] * inv) : (ushort)0;
      }
    }
  }
}

// ---------------------------------------------------------------------------
// mfma_ctx: fused ctx GEMM. A=Vh[bh] [1024,256], B=P_b[bh] [240,256], K=256.
// ---------------------------------------------------------------------------
__global__ __launch_bounds__(256) void mfma_ctx(const ushort* __restrict__ V,
                                                const ushort* __restrict__ P,
                                                ushort* __restrict__ ctx2) {
  const int h = blockIdx.y, b = blockIdx.z;
  const ushort* A  = V + (((long)b * H_ + h) * 1024) * 256;
  const ushort* Bm = P + (((long)b * H_ + h) * 240) * 256;

  const int m0 = (blockIdx.x >> 1) * 128;
  const int n0 = (blockIdx.x & 1) * 128;
  const int tid = threadIdx.x;
  const int l = tid & 63, w = tid >> 6;
  const int wy = w >> 1, wx = w & 1;

  __shared__ __align__(16) ushort As[128 * 32];
  __shared__ __align__(16) ushort Bs[128 * 32];

  f32x4 acc[4][4];
  #pragma unroll
  for (int i = 0; i < 4; ++i)
    #pragma unroll
    for (int j = 0; j < 4; ++j) acc[i][j] = (f32x4)0.f;

  const int srow = tid >> 2;
  const int skc  = (tid & 3) * 8;
  int rb0 = n0 + srow;      rb0 = rb0 < 240 ? rb0 : 239;
  int rb1 = n0 + srow + 64; rb1 = rb1 < 240 ? rb1 : 239;
  const ushort* a0 = A  + (long)(m0 + srow) * 256 + skc;
  const ushort* a1 = A  + (long)(m0 + srow + 64) * 256 + skc;
  const ushort* b0 = Bm + (long)rb0 * 256 + skc;
  const ushort* b1 = Bm + (long)rb1 * 256 + skc;
  ushort* lA0 = As + srow * 32 + skc;
  ushort* lA1 = As + (srow + 64) * 32 + skc;
  ushort* lB0 = Bs + srow * 32 + skc;
  ushort* lB1 = Bs + (srow + 64) * 32 + skc;

  const ushort* arp = As + (wy * 64 + (l & 15)) * 32 + (l >> 4) * 8;
  const ushort* brp = Bs + (wx * 64 + (l & 15)) * 32 + (l >> 4) * 8;

  for (int k0 = 0; k0 < 256; k0 += 32) {
    __syncthreads();
    gload16(a0 + k0, lA0);
    gload16(a1 + k0, lA1);
    gload16(b0 + k0, lB0);
    gload16(b1 + k0, lB1);
    __syncthreads();
    bf16x8 af[4], bfr[4];
    #pragma unroll
    for (int i = 0; i < 4; ++i) af[i]  = *(const bf16x8*)(arp + i * 512);
    #pragma unroll
    for (int j = 0; j < 4; ++j) bfr[j] = *(const bf16x8*)(brp + j * 512);
    #pragma unroll
    for (int i = 0; i < 4; ++i)
      #pragma unroll
      for (int j = 0; j < 4; ++j)
        acc[i][j] = __builtin_amdgcn_mfma_f32_16x16x32_bf16(af[i], bfr[j], acc[i][j], 0, 0, 0);
  }

  const int quad = l >> 4, lc = l & 15;
  const int dss[4] = {16, 32, 64, 128};
  const int qf[4]  = {0, 16, 48, 112};
  const int cf[4]  = {0, 64, 192, 448};
  #pragma unroll
  for (int i = 0; i < 4; ++i) {
    #pragma unroll
    for (int r = 0; r < 4; ++r) {
      int row = m0 + wy * 64 + i * 16 + quad * 4 + r;
      ushort* Cr = ctx2 + ((long)b * N_ + row) * 960;
      #pragma unroll
      for (int j = 0; j < 4; ++j) {
        int col = n0 + wx * 64 + j * 16 + lc;
        if (col < 240) {
          int s = col < 16 ? 0 : col < 48 ? 1 : col < 112 ? 2 : 3;
          int chan = cf[s] + h * dss[s] + (col - qf[s]);
          Cr[chan] = f2b(acc[i][j][r]);
        }
      }
    }
  }
}

// ---------------------------------------------------------------------------
// mfma_oproj: grouped out-projection, one dispatch for all 4 scales.
// ---------------------------------------------------------------------------
__global__ __launch_bounds__(256) void mfma_oproj(const ushort* __restrict__ ctx2,
                                                  const ushort* __restrict__ Wo_b,
                                                  float* __restrict__ out) {
  const int bx = blockIdx.x;
  int s = bx < 128 ? 0 : bx < 256 ? 1 : bx < 512 ? 2 : 3;
  const int sbase[4] = {0, 128, 256, 512};
  const int cs_[4]   = {64, 128, 256, 512};
  const int coff_[4] = {0, 64, 192, 448};
  const int wo_[4]   = {0, 4096, 20480, 86016};
  const long oo_[4]  = {0, 1048576, 3145728, 7340032};
  const int c = cs_[s];
  const int nt = (c + 127) >> 7;
  const int local = bx - sbase[s];
  const int m0 = (local / nt) * 128;
  const int n0 = (local % nt) * 128;

  const ushort* A  = ctx2 + coff_[s];
  const ushort* Bm = Wo_b + wo_[s];
  float* C = out + oo_[s];
  const int K = c, Nn = c;

  const int tid = threadIdx.x;
  const int l = tid & 63, w = tid >> 6;
  const int wy = w >> 1, wx = w & 1;

  __shared__ __align__(16) ushort As[128 * 32];
  __shared__ __align__(16) ushort Bs[128 * 32];

  f32x4 acc[4][4];
  #pragma unroll
  for (int i = 0; i < 4; ++i)
    #pragma unroll
    for (int j = 0; j < 4; ++j) acc[i][j] = (f32x4)0.f;

  const int srow = tid >> 2;
  const int skc  = (tid & 3) * 8;
  int rb0 = n0 + srow;      rb0 = rb0 < Nn ? rb0 : Nn - 1;
  int rb1 = n0 + srow + 64; rb1 = rb1 < Nn ? rb1 : Nn - 1;
  const ushort* a0 = A  + (long)(m0 + srow) * 960 + skc;
  const ushort* a1 = A  + (long)(m0 + srow + 64) * 960 + skc;
  const ushort* b0 = Bm + (long)rb0 * c + skc;
  const ushort* b1 = Bm + (long)rb1 * c + skc;
  ushort* lA0 = As + srow * 32 + skc;
  ushort* lA1 = As + (srow + 64) * 32 + skc;
  ushort* lB0 = Bs + srow * 32 + skc;
  ushort* lB1 = Bs + (srow + 64) * 32 + skc;

  const ushort* arp = As + (wy * 64 + (l & 15)) * 32 + (l >> 4) * 8;
  const ushort* brp = Bs + (wx * 64 + (l & 15)) * 32 + (l >> 4) * 8;

  for (int k0 = 0; k0 < K; k0 += 32) {
    __syncthreads();
    gload16(a0 + k0, lA0);
    gload16(a1 + k0, lA1);
    gload16(b0 + k0, lB0);
    gload16(b1 + k0, lB1);
    __syncthreads();
    bf16x8 af[4], bfr[4];
    #pragma unroll
    for (int i = 0; i < 4; ++i) af[i]  = *(const bf16x8*)(arp + i * 512);
    #pragma unroll
    for (int j = 0; j < 4; ++j) bfr[j] = *(const bf16x8*)(brp + j * 512);
    #pragma unroll
    for (int i = 0; i < 4; ++i)
      #pragma unroll
      for (int j = 0; j < 4; ++j)
        acc[i][j] = __builtin_amdgcn_mfma_f32_16x16x32_bf16(af[i], bfr[j], acc[i][j], 0, 0, 0);
  }

  const int quad = l >> 4, lc = l & 15;
  #pragma unroll
  for (int i = 0; i < 4; ++i) {
    #pragma unroll
    for (int r = 0; r < 4; ++r) {
      int row = m0 + wy * 64 + i * 16 + quad * 4 + r;
      float* Cr = C + (long)row * c;
      #pragma unroll
      for (int j = 0; j < 4; ++j) {
        int col = n0 + wx * 64 + j * 16 + lc;
        if (col < Nn) Cr[col] = acc[i][j][r];
      }
    }
  }
}

// ---------------------------------------------------------------------------
// launch — R8 resubmission (infra flake): Q_T/Kh_T relocated into d_out
// (62.91 MB, exact fit; dead before mfma_oproj overwrites d_out). Single-
// variable test of d_ws-vs-d_out placement; all kernels identical to R5.
// ---------------------------------------------------------------------------
extern "C" void kernel_launch(void* const* d_in, const int* in_sizes, int n_in,
                              void* d_out, int out_size, void* d_ws, size_t ws_size,
                              hipStream_t stream) {
  const float* emb[4] = {(const float*)d_in[0], (const float*)d_in[1],
                         (const float*)d_in[2], (const float*)d_in[3]};
  const float* emb_all = (const float*)d_in[4];
  const float* Wq[4] = {(const float*)d_in[5], (const float*)d_in[6],
                        (const float*)d_in[7], (const float*)d_in[8]};
  const float* Wk = (const float*)d_in[9];
  const float* Wv = (const float*)d_in[10];
  const float* Wo[4] = {(const float*)d_in[11], (const float*)d_in[12],
                        (const float*)d_in[13], (const float*)d_in[14]};
  float* out = (float*)d_out;

  ushort* wsb     = (ushort*)d_ws;
  ushort* ctx2    = wsb;                      // [B,N,960]
  ushort* P_b     = wsb + 16777216;           // [64,240,256]
  ushort* Vh      = wsb + 65011712;           // [B,H,1024,256]
  ushort* wts     = wsb + 81788928;           // 716800: Wk_b|Wv_b|Wq_bd|Wo_b
  ushort* Wk_b  = wts;
  ushort* Wv_b  = wts + 61440;
  ushort* Wq_bd = wts + 122880;
  ushort* Wo_b  = wts + 368640;
  // Q_T/Kh_T live in d_out: 2 x 15,728,640 ushorts = 62,914,560 B = out_size.
  ushort* Q_T   = (ushort*)d_out;
  ushort* Kh_T  = (ushort*)d_out + 15728640;

  const float alpha_s = 1.0f / sqrtf(960.0f);

  conv_weights<<<dim3(2800), 256, 0, stream>>>(Wk, Wv, Wq[0], Wq[1], Wq[2], Wq[3],
                                               Wo[0], Wo[1], Wo[2], Wo[3], wts);

  // merged K/V/Q projections (R5 staged cores; Q_T/Kh_T -> d_out)
  mfma_proj<<<dim3(3072), 256, 0, stream>>>(emb_all, emb[0], emb[1], emb[2], emb[3],
                                            Wk_b, Wv_b, Wq_bd, Kh_T, Vh, Q_T);

  // fused scores + InstanceNorm + softmax -> P (reads d_out, writes d_ws)
  fused_sm<<<dim3(4, 64), 512, 0, stream>>>(Q_T, Kh_T, P_b, alpha_s);

  // fused ctx (d_ws only)
  mfma_ctx<<<dim3(16, H_, B_), 256, 0, stream>>>(Vh, P_b, ctx2);

  // grouped out-proj — overwrites d_out (Q_T/Kh_T dead by now)
  mfma_oproj<<<dim3(1024), 256, 0, stream>>>(ctx2, Wo_b, out);
}